// Round 13
// baseline (88.414 us; speedup 1.0000x reference)
//
#include <hip/hip_runtime.h>
#include <math.h>

#define NN 10000
#define NE 320000
#define IN_DIM 512
#define FEAT_DIM 128
#define OD 64
#define NH 8
#define ZD 512          // OD*HEADS
#define NEG 0.01f
#define ZSCALE 16.0f

typedef __attribute__((ext_vector_type(8))) __bf16 bf16x8;
typedef __attribute__((ext_vector_type(4))) float f32x4;

__device__ __forceinline__ unsigned short f2b(float f) {
  __bf16 b = (__bf16)f;
  return __builtin_bit_cast(unsigned short, b);
}
__device__ __forceinline__ float bs2f(unsigned short u) {
  unsigned int x = ((unsigned int)u) << 16;
  return __builtin_bit_cast(float, x);
}
// signed-int8 lane k of a uint2 -> float
__device__ __forceinline__ float s8f(uint2 u, int k) {
  unsigned w = (k < 4) ? u.x : u.y;
  int kk = k & 3;
  return (float)((int)(w << ((3 - kk) * 8)) >> 24);
}
__device__ __forceinline__ uint4 pack8(float4 a, float4 b) {
  uint4 r;
  r.x = (unsigned)f2b(a.x) | ((unsigned)f2b(a.y) << 16);
  r.y = (unsigned)f2b(a.z) | ((unsigned)f2b(a.w) << 16);
  r.z = (unsigned)f2b(b.x) | ((unsigned)f2b(b.y) << 16);
  r.w = (unsigned)f2b(b.z) | ((unsigned)f2b(b.w) << 16);
  return r;
}

__device__ __forceinline__ void gload16(const void* g, void* l) {
  __builtin_amdgcn_global_load_lds((const __attribute__((address_space(1))) unsigned int*)g,
                                   (__attribute__((address_space(3))) unsigned int*)l, 16, 0, 0);
}

// ---------- prep (small): w_fc transpose->bf16 | wfab (bf16 B^T, padded) | CSR rows ----------
#define PREP_WT  256
#define PREP_WFA (PREP_WT + 8)
#define PREP_ALL (PREP_WFA + 40)
__global__ __launch_bounds__(256) void k_prep(const float* __restrict__ w_fc,
    const float* __restrict__ w_feat, const float* __restrict__ w_attn,
    const int* __restrict__ dst, unsigned short* __restrict__ wt,
    unsigned short* __restrict__ wfab, int* __restrict__ row_start) {
  const int bid = blockIdx.x, t = threadIdx.x;
  if (bid < PREP_WT) {
    __shared__ float tile[32][33];
    const int tx = (bid & 15) * 32, ty = (bid >> 4) * 32;
    const int r = t >> 3, c4 = (t & 7) * 4;
    float4 v = *(const float4*)(w_fc + (size_t)(ty + r) * ZD + tx + c4);
    tile[r][c4 + 0] = v.x; tile[r][c4 + 1] = v.y; tile[r][c4 + 2] = v.z; tile[r][c4 + 3] = v.w;
    __syncthreads();
    ushort4 o = make_ushort4(f2b(tile[c4 + 0][r]), f2b(tile[c4 + 1][r]),
                             f2b(tile[c4 + 2][r]), f2b(tile[c4 + 3][r]));
    *(ushort4*)(wt + (size_t)(tx + r) * IN_DIM + ty + c4) = o;
  } else if (bid < PREP_WFA) {
    // wfab[head][feat] = bf16( sum_d w_feat[feat][head*64+d] * a_feat[d] ); heads 8..15 = 0
    int tid = (bid - PREP_WT) * 256 + t;
    if (tid < FEAT_DIM * NH) {
      int f = tid >> 3, hh = tid & 7;
      const float* wr = w_feat + (size_t)f * ZD + hh * OD;
      const float* a  = w_attn + 2 * OD;
      float s = 0.f;
      #pragma unroll 8
      for (int d = 0; d < OD; ++d) s += wr[d] * a[d];
      wfab[hh * FEAT_DIM + f] = f2b(s);
    } else if (tid < 2 * FEAT_DIM * NH) {
      wfab[tid] = 0;   // covers rows 8..15
    }
  } else {
    int n = (bid - PREP_WFA) * 256 + t;
    if (n <= NN) {
      int lo = 0, hi = NE;
      while (lo < hi) { int mid = (lo + hi) >> 1; if (dst[mid] < n) lo = mid + 1; else hi = mid; }
      row_start[n] = lo;
    }
  }
}

// ---------- fused: [0,316) bf16-MFMA gemm (fp32-A reg-staged; int8 z out) | [316,5316) e_feat via MFMA ----------
#define GEMM_BLOCKS 316   // 79 * 4
__global__ __launch_bounds__(256) void k_fused(const float* __restrict__ h,
    const unsigned short* __restrict__ Bt, const float* __restrict__ w_attn,
    const float* __restrict__ dep_emb, const unsigned short* __restrict__ wfab,
    signed char* __restrict__ zq, float* __restrict__ s_src,
    float* __restrict__ s_dst, unsigned short* __restrict__ e_feat) {
  __shared__ __align__(16) char smem[16384];
  const int bid = blockIdx.x, t = threadIdx.x;
  const int lane = t & 63, wave = t >> 6;
  const int fr = lane & 15, kq = lane >> 4;

  if (bid < GEMM_BLOCKS) {
    // ---- GEMM role ----
    unsigned short* As = (unsigned short*)smem;            // 8 KB
    unsigned short* Bs = (unsigned short*)(smem + 8192);   // 8 KB
    const int m0 = (bid % 79) * 128;
    const int n0 = (bid / 79) * 128;
    const int wr = (wave >> 1) * 64, wc = (wave & 1) * 64;

    f32x4 acc[4][4] = {};

    const int idx0 = t, idx1 = t + 256;
    const int r0 = m0 + (idx0 & 127), r1 = m0 + (idx1 & 127);
    const float* gaf0 = h + (size_t)r0 * IN_DIM + (idx0 >> 7) * 8;
    const float* gaf1 = h + (size_t)r1 * IN_DIM + (idx1 >> 7) * 8;
    const unsigned short* gb0 = Bt + (size_t)(n0 + (idx0 & 127)) * IN_DIM + (idx0 >> 7) * 8;
    const unsigned short* gb1 = Bt + (size_t)(n0 + (idx1 & 127)) * IN_DIM + (idx1 >> 7) * 8;
    unsigned short* lb0 = &Bs[idx0 * 8];
    unsigned short* lb1 = &Bs[idx1 * 8];

    for (int k0 = 0; k0 < IN_DIM; k0 += 32) {
      gload16(gb0 + k0, lb0);
      gload16(gb1 + k0, lb1);
      // A: reg-stage fp32 -> bf16 (zero-pad rows >= NN)
      uint4 p0 = make_uint4(0, 0, 0, 0), p1 = make_uint4(0, 0, 0, 0);
      if (r0 < NN)
        p0 = pack8(*(const float4*)(gaf0 + k0), *(const float4*)(gaf0 + k0 + 4));
      if (r1 < NN)
        p1 = pack8(*(const float4*)(gaf1 + k0), *(const float4*)(gaf1 + k0 + 4));
      *(uint4*)&As[idx0 * 8] = p0;
      *(uint4*)&As[idx1 * 8] = p1;
      __syncthreads();
      bf16x8 a[4], b[4];
      #pragma unroll
      for (int m = 0; m < 4; m++)
        a[m] = *(const bf16x8*)&As[(kq * 128 + wr + m * 16 + fr) * 8];
      #pragma unroll
      for (int n = 0; n < 4; n++)
        b[n] = *(const bf16x8*)&Bs[(kq * 128 + wc + n * 16 + fr) * 8];
      #pragma unroll
      for (int m = 0; m < 4; m++)
        #pragma unroll
        for (int n = 0; n < 4; n++)
          acc[m][n] = __builtin_amdgcn_mfma_f32_16x16x32_bf16(a[m], b[n], acc[m][n], 0, 0, 0);
      __syncthreads();
    }

    float as_[4], ad_[4];
    #pragma unroll
    for (int n = 0; n < 4; n++) {
      as_[n] = w_attn[n * 16 + fr];
      ad_[n] = w_attn[OD + n * 16 + fr];
    }
    const int crow = kq * 4;
    const int ccol = lane & 15;
    const int hh = (n0 + wc) >> 6;

    #pragma unroll
    for (int m = 0; m < 4; m++) {
      #pragma unroll
      for (int n = 0; n < 4; n++) {
        int row = m0 + wr + m * 16 + crow;
        int col = n0 + wc + n * 16 + ccol;
        #pragma unroll
        for (int j = 0; j < 4; j++)
          if (row + j < NN) {
            int qv = (int)rintf(acc[m][n][j] * ZSCALE);
            qv = qv > 127 ? 127 : (qv < -127 ? -127 : qv);
            zq[(size_t)(row + j) * ZD + col] = (signed char)qv;
          }
      }
      float sp[4] = {0.f, 0.f, 0.f, 0.f}, sd[4] = {0.f, 0.f, 0.f, 0.f};
      #pragma unroll
      for (int n = 0; n < 4; n++)
        #pragma unroll
        for (int j = 0; j < 4; j++) {
          sp[j] = fmaf(acc[m][n][j], as_[n], sp[j]);
          sd[j] = fmaf(acc[m][n][j], ad_[n], sd[j]);
        }
      #pragma unroll
      for (int o = 1; o < 16; o <<= 1)
        #pragma unroll
        for (int j = 0; j < 4; j++) {
          sp[j] += __shfl_xor(sp[j], o);
          sd[j] += __shfl_xor(sd[j], o);
        }
      if (fr == 0) {
        int row = m0 + wr + m * 16 + crow;
        #pragma unroll
        for (int j = 0; j < 4; j++)
          if (row + j < NN) {
            s_src[(size_t)(row + j) * NH + hh] = sp[j];
            s_dst[(size_t)(row + j) * NH + hh] = sd[j];
          }
      }
    }
  } else {
    // ---- edge-feature role: e_feat[64 edges][8 heads] (bf16) = dep[64][128] @ wfab^T via MFMA ----
    const int erow = (bid - GEMM_BLOCKS) * 64 + wave * 16 + fr;
    const float* arow = dep_emb + (size_t)erow * FEAT_DIM;
    f32x4 acc = {};
    #pragma unroll
    for (int kk = 0; kk < 4; kk++) {
      float4 v0 = *(const float4*)(arow + kk * 32 + kq * 8);
      float4 v1 = *(const float4*)(arow + kk * 32 + kq * 8 + 4);
      bf16x8 a;
      a[0] = (__bf16)v0.x; a[1] = (__bf16)v0.y; a[2] = (__bf16)v0.z; a[3] = (__bf16)v0.w;
      a[4] = (__bf16)v1.x; a[5] = (__bf16)v1.y; a[6] = (__bf16)v1.z; a[7] = (__bf16)v1.w;
      bf16x8 b = *(const bf16x8*)&wfab[fr * FEAT_DIM + kk * 32 + kq * 8];
      acc = __builtin_amdgcn_mfma_f32_16x16x32_bf16(a, b, acc, 0, 0, 0);
    }
    // C layout: col = lane&15 (head), row = kq*4 + j (edge within 16-tile)
    if (fr < NH) {
      const int ebase = (bid - GEMM_BLOCKS) * 64 + wave * 16 + kq * 4;
      #pragma unroll
      for (int j = 0; j < 4; j++)
        e_feat[(size_t)(ebase + j) * NH + fr] = f2b(acc[j]);
    }
  }
}

// ---------- wave-per-node: score + online softmax + 4-deep int8 gather ----------
#define CH2 64
__global__ __launch_bounds__(256) void k_agg(const unsigned short* __restrict__ ef,
    const int* __restrict__ src, const int* __restrict__ row_start,
    const float* __restrict__ s_src, const float* __restrict__ s_dst,
    const signed char* __restrict__ zq, float* __restrict__ out) {
  __shared__ float els[4 * CH2 * NH];   // per-wave exp'd scores [edge][head]
  __shared__ int   src_s[4 * CH2];
  const int t = threadIdx.x;
  const int w = t >> 6, l = t & 63;
  const int n = blockIdx.x * 4 + w;
  const int es = l >> 3;        // edge slot (score phase)
  const int hs = l & 7;         // head (score phase)
  const int hc = l >> 3;        // head owning cols [8l, 8l+8)  (gather phase)
  float* myels = els + w * (CH2 * NH);
  int*   mysrc = src_s + w * CH2;

  const int start = row_start[n], end = row_start[n + 1];
  const float sdn = s_dst[(size_t)n * NH + hs];
  float m = -INFINITY, den = 0.f;
  float acc_e[8] = {0.f,0.f,0.f,0.f,0.f,0.f,0.f,0.f};
  float acc_o[8] = {0.f,0.f,0.f,0.f,0.f,0.f,0.f,0.f};
  const signed char* zcol = zq + l * 8;

  for (int c0 = start; c0 < end; c0 += CH2) {
    const int cn = min(CH2, end - c0);
    if (l < cn) mysrc[l] = src[c0 + l];
    // --- score phase: lane = (edge es, head hs) ---
    float e_r[CH2 / 8];
    float mchunk = -INFINITY;
    #pragma unroll
    for (int p = 0; p < CH2 / 8; p++) {
      int i = p * 8 + es;
      float e = -INFINITY;
      if (i < cn) {
        int sid = mysrc[i];
        e = bs2f(ef[(size_t)(c0 + i) * NH + hs]) + s_src[(size_t)sid * NH + hs] + sdn;
        e = e >= 0.f ? e : NEG * e;
      }
      e_r[p] = e;
      mchunk = fmaxf(mchunk, e);
    }
    mchunk = fmaxf(mchunk, __shfl_xor(mchunk, 8));
    mchunk = fmaxf(mchunk, __shfl_xor(mchunk, 16));
    mchunk = fmaxf(mchunk, __shfl_xor(mchunk, 32));
    float mn = fmaxf(m, mchunk);
    float dc = 0.f;
    #pragma unroll
    for (int p = 0; p < CH2 / 8; p++) {
      float ex = __expf(e_r[p] - mn);          // exp(-inf - mn) = 0 for invalid slots
      dc += ex;
      myels[(p * 8 + es) * NH + hs] = ex;
    }
    dc += __shfl_xor(dc, 8);
    dc += __shfl_xor(dc, 16);
    dc += __shfl_xor(dc, 32);
    float rs = __expf(m - mn);
    den = den * rs + dc;
    m = mn;
    // --- gather phase: lane = cols [8l,8l+8), head hc; 4 int8-row loads in flight ---
    float rs_c = __shfl(rs, hc);
    #pragma unroll
    for (int j = 0; j < 8; j++) { acc_e[j] *= rs_c; acc_o[j] *= rs_c; }
    int i = 0;
    for (; i + 4 <= cn; i += 4) {
      int s0 = mysrc[i], s1 = mysrc[i + 1], s2 = mysrc[i + 2], s3 = mysrc[i + 3];
      float w0 = myels[i * NH + hc];
      float w1 = myels[(i + 1) * NH + hc];
      float w2 = myels[(i + 2) * NH + hc];
      float w3 = myels[(i + 3) * NH + hc];
      uint2 u0 = *(const uint2*)(zcol + ((size_t)s0 << 9));
      uint2 u1 = *(const uint2*)(zcol + ((size_t)s1 << 9));
      uint2 u2 = *(const uint2*)(zcol + ((size_t)s2 << 9));
      uint2 u3 = *(const uint2*)(zcol + ((size_t)s3 << 9));
      #pragma unroll
      for (int j = 0; j < 8; j++) acc_e[j] = fmaf(w0, s8f(u0, j), acc_e[j]);
      #pragma unroll
      for (int j = 0; j < 8; j++) acc_o[j] = fmaf(w1, s8f(u1, j), acc_o[j]);
      #pragma unroll
      for (int j = 0; j < 8; j++) acc_e[j] = fmaf(w2, s8f(u2, j), acc_e[j]);
      #pragma unroll
      for (int j = 0; j < 8; j++) acc_o[j] = fmaf(w3, s8f(u3, j), acc_o[j]);
    }
    for (; i < cn; i++) {
      int s0 = mysrc[i];
      float w0 = myels[i * NH + hc];
      uint2 u0 = *(const uint2*)(zcol + ((size_t)s0 << 9));
      #pragma unroll
      for (int j = 0; j < 8; j++) acc_e[j] = fmaf(w0, s8f(u0, j), acc_e[j]);
    }
  }
  float den_c = __shfl(den, hc);
  float inv = den_c > 0.f ? 1.f / (den_c * ZSCALE) : 0.f;   // fold 1/16 dequant
  float4 o0, o1;
  o0.x = (acc_e[0] + acc_o[0]) * inv; o0.y = (acc_e[1] + acc_o[1]) * inv;
  o0.z = (acc_e[2] + acc_o[2]) * inv; o0.w = (acc_e[3] + acc_o[3]) * inv;
  o1.x = (acc_e[4] + acc_o[4]) * inv; o1.y = (acc_e[5] + acc_o[5]) * inv;
  o1.z = (acc_e[6] + acc_o[6]) * inv; o1.w = (acc_e[7] + acc_o[7]) * inv;
  float* orow = out + (size_t)n * ZD + l * 8;
  *(float4*)orow = o0;
  *(float4*)(orow + 4) = o1;
}

extern "C" void kernel_launch(void* const* d_in, const int* in_sizes, int n_in,
                              void* d_out, int out_size, void* d_ws, size_t ws_size,
                              hipStream_t stream) {
  const float* h      = (const float*)d_in[0];
  const float* dep    = (const float*)d_in[1];
  const int*   src    = (const int*)d_in[2];
  const int*   dst    = (const int*)d_in[3];
  const float* w_fc   = (const float*)d_in[4];
  const float* w_feat = (const float*)d_in[5];
  const float* w_attn = (const float*)d_in[6];
  float* out = (float*)d_out;

  char* ws = (char*)d_ws;
  size_t off = 0;
  auto alloc = [&](size_t bytes) { void* p = ws + off; off = (off + bytes + 63) & ~(size_t)63; return p; };
  float* s_src  = (float*)alloc((size_t)NN * NH * 4);
  float* s_dst  = (float*)alloc((size_t)NN * NH * 4);
  unsigned short* e_feat = (unsigned short*)alloc((size_t)NE * NH * 2);  // bf16 edge-major
  unsigned short* wfab = (unsigned short*)alloc(2 * FEAT_DIM * NH * 2);  // [16][128] bf16 B^T
  int*   row_st = (int*)alloc((NN + 2) * 4);
  signed char* zq = (signed char*)alloc((size_t)NN * ZD);   // int8 z, scale 16
  unsigned short* wt = (unsigned short*)alloc((size_t)IN_DIM * ZD * 2);

  k_prep <<<PREP_ALL, 256, 0, stream>>>(w_fc, w_feat, w_attn, dst, wt, wfab, row_st);
  k_fused<<<GEMM_BLOCKS + NE / 64, 256, 0, stream>>>(h, wt, w_attn, dep, wfab,
                                                     zq, s_src, s_dst, e_feat);
  k_agg  <<<NN / 4, 256, 0, stream>>>(e_feat, src, row_st, s_src, s_dst, zq, out);
}

// Round 14
// 82.859 us; speedup vs baseline: 1.0671x; 1.0671x over previous
//
#include <hip/hip_runtime.h>
#include <math.h>

#define NN 10000
#define NPAD 10112     // 79*128
#define NE 320000
#define IN_DIM 512
#define FEAT_DIM 128
#define OD 64
#define NH 8
#define ZD 512          // OD*HEADS
#define NEG 0.01f
#define ZSCALE 16.0f

typedef __attribute__((ext_vector_type(8))) __bf16 bf16x8;
typedef __attribute__((ext_vector_type(4))) float f32x4;

__device__ __forceinline__ unsigned short f2b(float f) {
  __bf16 b = (__bf16)f;
  return __builtin_bit_cast(unsigned short, b);
}
__device__ __forceinline__ float bs2f(unsigned short u) {
  unsigned int x = ((unsigned int)u) << 16;
  return __builtin_bit_cast(float, x);
}
// signed-int8 lane k of a uint2 -> float
__device__ __forceinline__ float s8f(uint2 u, int k) {
  unsigned w = (k < 4) ? u.x : u.y;
  int kk = k & 3;
  return (float)((int)(w << ((3 - kk) * 8)) >> 24);
}

__device__ __forceinline__ void gload16(const void* g, void* l) {
  __builtin_amdgcn_global_load_lds((const __attribute__((address_space(1))) unsigned int*)g,
                                   (__attribute__((address_space(3))) unsigned int*)l, 16, 0, 0);
}

// ---------- fused prep: h->bf16 | w_fc transpose->bf16 | wfab (bf16 B^T, padded) | CSR rows ----------
#define PREP_H2B 2528
#define PREP_WT  (PREP_H2B + 256)
#define PREP_WFA (PREP_WT + 8)
#define PREP_ALL (PREP_WFA + 40)
__global__ __launch_bounds__(256) void k_prep(const float* __restrict__ h,
    const float* __restrict__ w_fc, const float* __restrict__ w_feat,
    const float* __restrict__ w_attn, const int* __restrict__ dst,
    unsigned short* __restrict__ hb, unsigned short* __restrict__ wt,
    unsigned short* __restrict__ wfab, int* __restrict__ row_start) {
  const int bid = blockIdx.x, t = threadIdx.x;
  if (bid < PREP_H2B) {
    size_t base = ((size_t)bid * 256 + t) * 8;
    int row = (int)(base >> 9);
    ushort4 o0, o1;
    if (row < NN) {
      float4 v0 = *(const float4*)(h + base);
      float4 v1 = *(const float4*)(h + base + 4);
      o0 = make_ushort4(f2b(v0.x), f2b(v0.y), f2b(v0.z), f2b(v0.w));
      o1 = make_ushort4(f2b(v1.x), f2b(v1.y), f2b(v1.z), f2b(v1.w));
    } else {
      o0 = make_ushort4(0, 0, 0, 0);
      o1 = make_ushort4(0, 0, 0, 0);
    }
    *(ushort4*)(hb + base) = o0;
    *(ushort4*)(hb + base + 4) = o1;
  } else if (bid < PREP_WT) {
    __shared__ float tile[32][33];
    const int b2 = bid - PREP_H2B;
    const int tx = (b2 & 15) * 32, ty = (b2 >> 4) * 32;
    const int r = t >> 3, c4 = (t & 7) * 4;
    float4 v = *(const float4*)(w_fc + (size_t)(ty + r) * ZD + tx + c4);
    tile[r][c4 + 0] = v.x; tile[r][c4 + 1] = v.y; tile[r][c4 + 2] = v.z; tile[r][c4 + 3] = v.w;
    __syncthreads();
    ushort4 o = make_ushort4(f2b(tile[c4 + 0][r]), f2b(tile[c4 + 1][r]),
                             f2b(tile[c4 + 2][r]), f2b(tile[c4 + 3][r]));
    *(ushort4*)(wt + (size_t)(tx + r) * IN_DIM + ty + c4) = o;
  } else if (bid < PREP_WFA) {
    // wfab[head][feat] = bf16( sum_d w_feat[feat][head*64+d] * a_feat[d] ); heads 8..15 = 0
    int tid = (bid - PREP_WT) * 256 + t;
    if (tid < FEAT_DIM * NH) {
      int f = tid >> 3, hh = tid & 7;
      const float* wr = w_feat + (size_t)f * ZD + hh * OD;
      const float* a  = w_attn + 2 * OD;
      float s = 0.f;
      #pragma unroll 8
      for (int d = 0; d < OD; ++d) s += wr[d] * a[d];
      wfab[hh * FEAT_DIM + f] = f2b(s);
    } else if (tid < 2 * FEAT_DIM * NH) {
      wfab[tid] = 0;   // covers rows 8..15
    }
  } else {
    int n = (bid - PREP_WFA) * 256 + t;
    if (n <= NN) {
      int lo = 0, hi = NE;
      while (lo < hi) { int mid = (lo + hi) >> 1; if (dst[mid] < n) lo = mid + 1; else hi = mid; }
      row_start[n] = lo;
    }
  }
}

// ---------- fused: [0,316) bf16-MFMA gemm (+score epilogue, int8 z out)  |  [316,5316) e_feat via MFMA ----------
#define GEMM_BLOCKS 316   // 79 * 4
__global__ __launch_bounds__(256) void k_fused(const unsigned short* __restrict__ A,
    const unsigned short* __restrict__ Bt, const float* __restrict__ w_attn,
    const float* __restrict__ dep_emb, const unsigned short* __restrict__ wfab,
    signed char* __restrict__ zq, float* __restrict__ s_src,
    float* __restrict__ s_dst, unsigned short* __restrict__ e_feat) {
  __shared__ __align__(16) char smem[16384];
  const int bid = blockIdx.x, t = threadIdx.x;
  const int lane = t & 63, wave = t >> 6;
  const int fr = lane & 15, kq = lane >> 4;

  if (bid < GEMM_BLOCKS) {
    // ---- GEMM role ----
    unsigned short* As = (unsigned short*)smem;            // 8 KB
    unsigned short* Bs = (unsigned short*)(smem + 8192);   // 8 KB
    const int m0 = (bid % 79) * 128;
    const int n0 = (bid / 79) * 128;
    const int wr = (wave >> 1) * 64, wc = (wave & 1) * 64;

    f32x4 acc[4][4] = {};

    const int idx0 = t, idx1 = t + 256;
    const unsigned short* ga0 = A + (size_t)(m0 + (idx0 & 127)) * IN_DIM + (idx0 >> 7) * 8;
    const unsigned short* ga1 = A + (size_t)(m0 + (idx1 & 127)) * IN_DIM + (idx1 >> 7) * 8;
    const unsigned short* gb0 = Bt + (size_t)(n0 + (idx0 & 127)) * IN_DIM + (idx0 >> 7) * 8;
    const unsigned short* gb1 = Bt + (size_t)(n0 + (idx1 & 127)) * IN_DIM + (idx1 >> 7) * 8;
    unsigned short* la0 = &As[idx0 * 8];
    unsigned short* la1 = &As[idx1 * 8];
    unsigned short* lb0 = &Bs[idx0 * 8];
    unsigned short* lb1 = &Bs[idx1 * 8];

    for (int k0 = 0; k0 < IN_DIM; k0 += 32) {
      gload16(ga0 + k0, la0);
      gload16(ga1 + k0, la1);
      gload16(gb0 + k0, lb0);
      gload16(gb1 + k0, lb1);
      __syncthreads();
      bf16x8 a[4], b[4];
      #pragma unroll
      for (int m = 0; m < 4; m++)
        a[m] = *(const bf16x8*)&As[(kq * 128 + wr + m * 16 + fr) * 8];
      #pragma unroll
      for (int n = 0; n < 4; n++)
        b[n] = *(const bf16x8*)&Bs[(kq * 128 + wc + n * 16 + fr) * 8];
      #pragma unroll
      for (int m = 0; m < 4; m++)
        #pragma unroll
        for (int n = 0; n < 4; n++)
          acc[m][n] = __builtin_amdgcn_mfma_f32_16x16x32_bf16(a[m], b[n], acc[m][n], 0, 0, 0);
      __syncthreads();
    }

    float as_[4], ad_[4];
    #pragma unroll
    for (int n = 0; n < 4; n++) {
      as_[n] = w_attn[n * 16 + fr];
      ad_[n] = w_attn[OD + n * 16 + fr];
    }
    const int crow = kq * 4;
    const int ccol = lane & 15;
    const int hh = (n0 + wc) >> 6;

    #pragma unroll
    for (int m = 0; m < 4; m++) {
      #pragma unroll
      for (int n = 0; n < 4; n++) {
        int row = m0 + wr + m * 16 + crow;
        int col = n0 + wc + n * 16 + ccol;
        #pragma unroll
        for (int j = 0; j < 4; j++)
          if (row + j < NN) {
            int qv = (int)rintf(acc[m][n][j] * ZSCALE);
            qv = qv > 127 ? 127 : (qv < -127 ? -127 : qv);
            zq[(size_t)(row + j) * ZD + col] = (signed char)qv;
          }
      }
      float sp[4] = {0.f, 0.f, 0.f, 0.f}, sd[4] = {0.f, 0.f, 0.f, 0.f};
      #pragma unroll
      for (int n = 0; n < 4; n++)
        #pragma unroll
        for (int j = 0; j < 4; j++) {
          sp[j] = fmaf(acc[m][n][j], as_[n], sp[j]);
          sd[j] = fmaf(acc[m][n][j], ad_[n], sd[j]);
        }
      #pragma unroll
      for (int o = 1; o < 16; o <<= 1)
        #pragma unroll
        for (int j = 0; j < 4; j++) {
          sp[j] += __shfl_xor(sp[j], o);
          sd[j] += __shfl_xor(sd[j], o);
        }
      if (fr == 0) {
        int row = m0 + wr + m * 16 + crow;
        #pragma unroll
        for (int j = 0; j < 4; j++)
          if (row + j < NN) {
            s_src[(size_t)(row + j) * NH + hh] = sp[j];
            s_dst[(size_t)(row + j) * NH + hh] = sd[j];
          }
      }
    }
  } else {
    // ---- edge-feature role: e_feat[64 edges][8 heads] (bf16) = dep[64][128] @ wfab^T via MFMA ----
    const int erow = (bid - GEMM_BLOCKS) * 64 + wave * 16 + fr;
    const float* arow = dep_emb + (size_t)erow * FEAT_DIM;
    f32x4 acc = {};
    #pragma unroll
    for (int kk = 0; kk < 4; kk++) {
      float4 v0 = *(const float4*)(arow + kk * 32 + kq * 8);
      float4 v1 = *(const float4*)(arow + kk * 32 + kq * 8 + 4);
      bf16x8 a;
      a[0] = (__bf16)v0.x; a[1] = (__bf16)v0.y; a[2] = (__bf16)v0.z; a[3] = (__bf16)v0.w;
      a[4] = (__bf16)v1.x; a[5] = (__bf16)v1.y; a[6] = (__bf16)v1.z; a[7] = (__bf16)v1.w;
      bf16x8 b = *(const bf16x8*)&wfab[fr * FEAT_DIM + kk * 32 + kq * 8];
      acc = __builtin_amdgcn_mfma_f32_16x16x32_bf16(a, b, acc, 0, 0, 0);
    }
    // C layout: col = lane&15 (head), row = kq*4 + j (edge within 16-tile)
    if (fr < NH) {
      const int ebase = (bid - GEMM_BLOCKS) * 64 + wave * 16 + kq * 4;
      #pragma unroll
      for (int j = 0; j < 4; j++)
        e_feat[(size_t)(ebase + j) * NH + fr] = f2b(acc[j]);
    }
  }
}

// ---------- wave-per-node: score + online softmax + 4-deep int8 gather ----------
#define CH2 64
__global__ __launch_bounds__(256) void k_agg(const unsigned short* __restrict__ ef,
    const int* __restrict__ src, const int* __restrict__ row_start,
    const float* __restrict__ s_src, const float* __restrict__ s_dst,
    const signed char* __restrict__ zq, float* __restrict__ out) {
  __shared__ float els[4 * CH2 * NH];   // per-wave exp'd scores [edge][head]
  __shared__ int   src_s[4 * CH2];
  const int t = threadIdx.x;
  const int w = t >> 6, l = t & 63;
  const int n = blockIdx.x * 4 + w;
  const int es = l >> 3;        // edge slot (score phase)
  const int hs = l & 7;         // head (score phase)
  const int hc = l >> 3;        // head owning cols [8l, 8l+8)  (gather phase)
  float* myels = els + w * (CH2 * NH);
  int*   mysrc = src_s + w * CH2;

  const int start = row_start[n], end = row_start[n + 1];
  const float sdn = s_dst[(size_t)n * NH + hs];
  float m = -INFINITY, den = 0.f;
  float acc_e[8] = {0.f,0.f,0.f,0.f,0.f,0.f,0.f,0.f};
  float acc_o[8] = {0.f,0.f,0.f,0.f,0.f,0.f,0.f,0.f};
  const signed char* zcol = zq + l * 8;

  for (int c0 = start; c0 < end; c0 += CH2) {
    const int cn = min(CH2, end - c0);
    if (l < cn) mysrc[l] = src[c0 + l];
    // --- score phase: lane = (edge es, head hs) ---
    float e_r[CH2 / 8];
    float mchunk = -INFINITY;
    #pragma unroll
    for (int p = 0; p < CH2 / 8; p++) {
      int i = p * 8 + es;
      float e = -INFINITY;
      if (i < cn) {
        int sid = mysrc[i];
        e = bs2f(ef[(size_t)(c0 + i) * NH + hs]) + s_src[(size_t)sid * NH + hs] + sdn;
        e = e >= 0.f ? e : NEG * e;
      }
      e_r[p] = e;
      mchunk = fmaxf(mchunk, e);
    }
    mchunk = fmaxf(mchunk, __shfl_xor(mchunk, 8));
    mchunk = fmaxf(mchunk, __shfl_xor(mchunk, 16));
    mchunk = fmaxf(mchunk, __shfl_xor(mchunk, 32));
    float mn = fmaxf(m, mchunk);
    float dc = 0.f;
    #pragma unroll
    for (int p = 0; p < CH2 / 8; p++) {
      float ex = __expf(e_r[p] - mn);          // exp(-inf - mn) = 0 for invalid slots
      dc += ex;
      myels[(p * 8 + es) * NH + hs] = ex;
    }
    dc += __shfl_xor(dc, 8);
    dc += __shfl_xor(dc, 16);
    dc += __shfl_xor(dc, 32);
    float rs = __expf(m - mn);
    den = den * rs + dc;
    m = mn;
    // --- gather phase: lane = cols [8l,8l+8), head hc; 4 int8-row loads in flight ---
    float rs_c = __shfl(rs, hc);
    #pragma unroll
    for (int j = 0; j < 8; j++) { acc_e[j] *= rs_c; acc_o[j] *= rs_c; }
    int i = 0;
    for (; i + 4 <= cn; i += 4) {
      int s0 = mysrc[i], s1 = mysrc[i + 1], s2 = mysrc[i + 2], s3 = mysrc[i + 3];
      float w0 = myels[i * NH + hc];
      float w1 = myels[(i + 1) * NH + hc];
      float w2 = myels[(i + 2) * NH + hc];
      float w3 = myels[(i + 3) * NH + hc];
      uint2 u0 = *(const uint2*)(zcol + ((size_t)s0 << 9));
      uint2 u1 = *(const uint2*)(zcol + ((size_t)s1 << 9));
      uint2 u2 = *(const uint2*)(zcol + ((size_t)s2 << 9));
      uint2 u3 = *(const uint2*)(zcol + ((size_t)s3 << 9));
      #pragma unroll
      for (int j = 0; j < 8; j++) acc_e[j] = fmaf(w0, s8f(u0, j), acc_e[j]);
      #pragma unroll
      for (int j = 0; j < 8; j++) acc_o[j] = fmaf(w1, s8f(u1, j), acc_o[j]);
      #pragma unroll
      for (int j = 0; j < 8; j++) acc_e[j] = fmaf(w2, s8f(u2, j), acc_e[j]);
      #pragma unroll
      for (int j = 0; j < 8; j++) acc_o[j] = fmaf(w3, s8f(u3, j), acc_o[j]);
    }
    for (; i < cn; i++) {
      int s0 = mysrc[i];
      float w0 = myels[i * NH + hc];
      uint2 u0 = *(const uint2*)(zcol + ((size_t)s0 << 9));
      #pragma unroll
      for (int j = 0; j < 8; j++) acc_e[j] = fmaf(w0, s8f(u0, j), acc_e[j]);
    }
  }
  float den_c = __shfl(den, hc);
  float inv = den_c > 0.f ? 1.f / (den_c * ZSCALE) : 0.f;   // fold 1/16 dequant
  float4 o0, o1;
  o0.x = (acc_e[0] + acc_o[0]) * inv; o0.y = (acc_e[1] + acc_o[1]) * inv;
  o0.z = (acc_e[2] + acc_o[2]) * inv; o0.w = (acc_e[3] + acc_o[3]) * inv;
  o1.x = (acc_e[4] + acc_o[4]) * inv; o1.y = (acc_e[5] + acc_o[5]) * inv;
  o1.z = (acc_e[6] + acc_o[6]) * inv; o1.w = (acc_e[7] + acc_o[7]) * inv;
  float* orow = out + (size_t)n * ZD + l * 8;
  *(float4*)orow = o0;
  *(float4*)(orow + 4) = o1;
}

extern "C" void kernel_launch(void* const* d_in, const int* in_sizes, int n_in,
                              void* d_out, int out_size, void* d_ws, size_t ws_size,
                              hipStream_t stream) {
  const float* h      = (const float*)d_in[0];
  const float* dep    = (const float*)d_in[1];
  const int*   src    = (const int*)d_in[2];
  const int*   dst    = (const int*)d_in[3];
  const float* w_fc   = (const float*)d_in[4];
  const float* w_feat = (const float*)d_in[5];
  const float* w_attn = (const float*)d_in[6];
  float* out = (float*)d_out;

  char* ws = (char*)d_ws;
  size_t off = 0;
  auto alloc = [&](size_t bytes) { void* p = ws + off; off = (off + bytes + 63) & ~(size_t)63; return p; };
  float* s_src  = (float*)alloc((size_t)NN * NH * 4);
  float* s_dst  = (float*)alloc((size_t)NN * NH * 4);
  unsigned short* e_feat = (unsigned short*)alloc((size_t)NE * NH * 2);  // bf16 edge-major
  unsigned short* wfab = (unsigned short*)alloc(2 * FEAT_DIM * NH * 2);  // [16][128] bf16 B^T
  int*   row_st = (int*)alloc((NN + 2) * 4);
  signed char* zq = (signed char*)alloc((size_t)NN * ZD);   // int8 z, scale 16
  unsigned short* hb = (unsigned short*)alloc((size_t)NPAD * IN_DIM * 2);
  unsigned short* wt = (unsigned short*)alloc((size_t)IN_DIM * ZD * 2);

  k_prep <<<PREP_ALL, 256, 0, stream>>>(h, w_fc, w_feat, w_attn, dst, hb, wt, wfab, row_st);
  k_fused<<<GEMM_BLOCKS + NE / 64, 256, 0, stream>>>(hb, wt, w_attn, dep, wfab,
                                                     zq, s_src, s_dst, e_feat);
  k_agg  <<<NN / 4, 256, 0, stream>>>(e_feat, src, row_st, s_src, s_dst, zq, out);
}